// Round 1
// baseline (127.656 us; speedup 1.0000x reference)
//
#include <hip/hip_runtime.h>

// GMELoss3D: fused 3D Sobel edge-magnitude MSE on [2,2,128,128,128] fp32 volumes.
//
// Math: x = sum_c img[:,c]  (channel sum, by linearity of conv)
//       g_k = conv3d(x, S_k) for 9 sobel stencils, SAME zero padding
//       mag = sqrt(sum_k g_k^2 + 1e-12) / C      (C = 2)
//       out = mean((mag_y - mag_yp)^2)           over B*H*W*D = 4,194,304 voxels
//
// All 9 stencils factor over s=[1,2,1], d=[-1,0,1], e=[1,1,1]:
//   Sx = s_z s_y d_x ; Sy = s_z d_y s_x ; Sz = d_z s_y s_x
//   Sd11 = s_z (d_x - d_y) ; Sd12 = s_z (d_x + d_y)
//   Sd21 = s_x (d_z - d_y) ; Sd22 = s_x (d_z + d_y)
//   Sd31 = s_y (d_x - d_z) ; Sd32 = s_y (d_x + d_z)
// => per z-plane we need only 7 2-D combos (C0..C6), then cheap z-combines.
// Signs don't matter (everything squared), so corr-vs-conv flip is irrelevant.

namespace {

constexpr int ZDIM = 128, YDIM = 128, XDIM = 128;   // (H, W, D); D contiguous
constexpr int TX = 32;            // tile extent along D (x)
constexpr int TY = 8;             // tile extent along W (y)
constexpr int ZC = 16;            // H-planes per block (z-march chunk)
constexpr int LW = TX + 2;        // LDS row stride (34)
constexpr int PLANE = (TY + 2) * LW;   // 340 floats per plane buffer
constexpr float INV_N = 1.0f / 4194304.0f;   // 1 / (B*H*W*D)

__global__ void zero_out_kernel(float* out) { *out = 0.0f; }

// 7 per-plane combos at (ty,tx) from the halo'd LDS plane.
__device__ __forceinline__ void plane_combos(const float* __restrict__ s,
                                             int ty, int tx, float* __restrict__ C) {
    float sx[3], dx[3], ex[3];
#pragma unroll
    for (int r = 0; r < 3; ++r) {
        const float a0 = s[(ty + r) * LW + tx + 0];
        const float a1 = s[(ty + r) * LW + tx + 1];
        const float a2 = s[(ty + r) * LW + tx + 2];
        const float t = a0 + a2;
        ex[r] = t + a1;               // e_x
        sx[r] = t + 2.0f * a1;        // s_x
        dx[r] = a2 - a0;              // d_x
    }
    C[0] = dx[0] + 2.0f * dx[1] + dx[2];   // s_y d_x
    C[1] = sx[2] - sx[0];                  // d_y s_x
    C[2] = sx[0] + 2.0f * sx[1] + sx[2];   // s_y s_x
    C[3] = dx[0] + dx[1] + dx[2];          // e_y d_x
    C[4] = ex[2] - ex[0];                  // d_y e_x
    C[5] = sx[0] + sx[1] + sx[2];          // e_y s_x
    C[6] = ex[0] + 2.0f * ex[1] + ex[2];   // s_y e_x
}

// half edge magnitude (mag / C with C=2) from 3 planes' combos
__device__ __forceinline__ float edge_mag_half(const float* __restrict__ Ca,
                                               const float* __restrict__ Cb,
                                               const float* __restrict__ Cc) {
    const float g1  = Ca[0] + 2.0f * Cb[0] + Cc[0];   // Sx
    const float g2  = Ca[1] + 2.0f * Cb[1] + Cc[1];   // Sy
    const float g3  = Cc[2] - Ca[2];                  // Sz
    const float Azx = Ca[3] + 2.0f * Cb[3] + Cc[3];   // s_z e_y d_x
    const float Azy = Ca[4] + 2.0f * Cb[4] + Cc[4];   // s_z d_y e_x
    const float Axz = Cc[5] - Ca[5];                  // d_z e_y s_x
    const float Axy = Ca[1] + Cb[1] + Cc[1];          // e_z d_y s_x
    const float Ayx = Ca[0] + Cb[0] + Cc[0];          // e_z s_y d_x
    const float Ayz = Cc[6] - Ca[6];                  // d_z s_y e_x
    const float g4 = Azx - Azy, g5 = Azx + Azy;       // Sd11, Sd12
    const float g6 = Axz - Axy, g7 = Axz + Axy;       // Sd21, Sd22
    const float g8 = Ayx - Ayz, g9 = Ayx + Ayz;       // Sd31, Sd32
    const float ssq = g1 * g1 + g2 * g2 + g3 * g3 + g4 * g4 + g5 * g5
                    + g6 * g6 + g7 * g7 + g8 * g8 + g9 * g9;
    return 0.5f * sqrtf(ssq + 1e-12f);
}

__global__ __launch_bounds__(TX * TY)
void gme_loss_kernel(const float* __restrict__ y,
                     const float* __restrict__ yp,
                     float* __restrict__ out) {
    const int tx = threadIdx.x;          // D axis within tile
    const int ty = threadIdx.y;          // W axis within tile
    const int tid = ty * TX + tx;        // 0..255

    const int bx = blockIdx.x;           // 64 tiles: 4 along D, 16 along W
    const int x0 = (bx & 3) * TX;
    const int y0 = (bx >> 2) * TY;
    const int z0 = blockIdx.y * ZC;      // H chunk
    const int b  = blockIdx.z;           // batch

    const int gy = y0 + ty;              // this thread's W coordinate

    __shared__ float sY[PLANE];
    __shared__ float sP[PLANE];
    __shared__ float red[4];

    const size_t cstride = (size_t)ZDIM * YDIM * XDIM;        // channel stride
    const size_t bbase   = (size_t)b * 2 * cstride;           // batch base (C=2)

    float CaY[7], CbY[7], CaP[7], CbP[7];
#pragma unroll
    for (int i = 0; i < 7; ++i) { CaY[i] = 0.f; CbY[i] = 0.f; CaP[i] = 0.f; CbP[i] = 0.f; }

    float acc = 0.0f;

    for (int zc = z0 - 1; zc <= z0 + ZC; ++zc) {
        __syncthreads();   // previous iteration's LDS reads complete
        // ---- stage channel-summed plane zc (with halo, SAME zero padding) ----
        if (zc >= 0 && zc < ZDIM) {
            const size_t zrow = bbase + (size_t)zc * YDIM * XDIM;
            for (int i = tid; i < PLANE; i += TX * TY) {
                const int ly = i / LW;
                const int lx = i - ly * LW;
                const int py = y0 - 1 + ly;
                const int px = x0 - 1 + lx;
                float vy = 0.0f, vp = 0.0f;
                if (py >= 0 && py < YDIM && px >= 0 && px < XDIM) {
                    const size_t idx = zrow + (size_t)py * XDIM + px;
                    vy = y[idx]  + y[idx + cstride];
                    vp = yp[idx] + yp[idx + cstride];
                }
                sY[i] = vy;
                sP[i] = vp;
            }
        } else {
            for (int i = tid; i < PLANE; i += TX * TY) { sY[i] = 0.f; sP[i] = 0.f; }
        }
        __syncthreads();

        // ---- per-plane 2-D combos (computed once per plane, cached in regs) ----
        float CcY[7], CcP[7];
        plane_combos(sY, ty, tx, CcY);
        plane_combos(sP, ty, tx, CcP);

        // ---- emit output plane zc-1 once its +1 neighbor plane is reduced ----
        if (zc >= z0 + 1) {
            const float my = edge_mag_half(CaY, CbY, CcY);
            const float mp = edge_mag_half(CaP, CbP, CcP);
            const float d = my - mp;
            acc += d * d;
        }

        // rotate plane combos
#pragma unroll
        for (int i = 0; i < 7; ++i) {
            CaY[i] = CbY[i]; CbY[i] = CcY[i];
            CaP[i] = CbP[i]; CbP[i] = CcP[i];
        }
        (void)gy;
    }

    // ---- block reduction: wave shuffle, then 4 partials through LDS ----
#pragma unroll
    for (int off = 32; off > 0; off >>= 1) acc += __shfl_down(acc, off);
    const int lane = tid & 63;
    const int wave = tid >> 6;
    if (lane == 0) red[wave] = acc;
    __syncthreads();
    if (tid == 0) {
        const float s = (red[0] + red[1] + red[2] + red[3]) * INV_N;
        atomicAdd(out, s);
    }
}

}  // namespace

extern "C" void kernel_launch(void* const* d_in, const int* in_sizes, int n_in,
                              void* d_out, int out_size, void* d_ws, size_t ws_size,
                              hipStream_t stream) {
    const float* y  = (const float*)d_in[0];
    const float* yp = (const float*)d_in[1];
    float* out = (float*)d_out;

    // d_out is poisoned before every launch: zero it first (same stream => ordered)
    zero_out_kernel<<<1, 1, 0, stream>>>(out);

    dim3 block(TX, TY, 1);                       // 256 threads
    dim3 grid((XDIM / TX) * (YDIM / TY),         // 4 * 16 = 64 (D,W) tiles
              ZDIM / ZC,                         // 8 H chunks
              2);                                // batch
    gme_loss_kernel<<<grid, block, 0, stream>>>(y, yp, out);
}

// Round 2
// 122.138 us; speedup vs baseline: 1.0452x; 1.0452x over previous
//
#include <hip/hip_runtime.h>

// GMELoss3D: fused 3D Sobel edge-magnitude MSE on [2,2,128,128,128] fp32 volumes.
// R2: float4 staging into double-buffered LDS, software-pipelined prefetch
// (1 barrier/iter), modulo-3 combo rotation w/ unroll 6, memset for out-zeroing.
//
// Separable decomposition: s=[1,2,1], d=[-1,0,1], e=[1,1,1].
//   Sx=s_z s_y d_x ; Sy=s_z d_y s_x ; Sz=d_z s_y s_x
//   Sd11/12 = s_z (e_y d_x ∓ d_y e_x) ; Sd21/22 = s_x-row (d_z e_y s_x ∓ e_z d_y s_x)
//   Sd31/32 = (e_z s_y d_x ∓ d_z s_y e_x)
// => 7 per-plane 2-D combos per volume, cheap z-combines. Signs irrelevant (squared).

namespace {

constexpr int ZDIM = 128, YDIM = 128, XDIM = 128;   // (H, W, D); D contiguous
constexpr int TX = 32, TY = 8, ZC = 16;
constexpr int LW = 40;                  // LDS row covers x0-4 .. x0+35 (float4-aligned)
constexpr int ROWS = TY + 2;            // 10
constexpr int PLANE = ROWS * LW;        // 400 floats per volume-plane buffer
constexpr int QPR = LW / 4;             // 10 float4 per row
constexpr int NSLOT = ROWS * QPR;       // 100 float4 slots per volume-plane
constexpr int YX = YDIM * XDIM;         // z-plane stride
constexpr size_t CS = (size_t)ZDIM * YX;  // channel stride
constexpr float INV_N = 1.0f / 4194304.0f;

__device__ __forceinline__ void plane_combos(const float* __restrict__ p,
                                             float* __restrict__ C) {
  float sx[3], dx[3], ex[3];
#pragma unroll
  for (int r = 0; r < 3; ++r) {
    const float a0 = p[r * LW + 0];
    const float a1 = p[r * LW + 1];
    const float a2 = p[r * LW + 2];
    const float t = a0 + a2;
    ex[r] = t + a1;                          // e_x
    sx[r] = __builtin_fmaf(2.0f, a1, t);     // s_x
    dx[r] = a2 - a0;                         // d_x
  }
  C[3] = (dx[0] + dx[2]) + dx[1];            // e_y d_x
  C[0] = C[3] + dx[1];                       // s_y d_x
  C[1] = sx[2] - sx[0];                      // d_y s_x
  C[5] = (sx[0] + sx[2]) + sx[1];            // e_y s_x
  C[2] = C[5] + sx[1];                       // s_y s_x
  C[4] = ex[2] - ex[0];                      // d_y e_x
  C[6] = __builtin_fmaf(2.0f, ex[1], ex[0] + ex[2]);   // s_y e_x
}

// half edge magnitude (mag / C, C=2) from 3 planes' combos (a=z-1, b=z, c=z+1)
__device__ __forceinline__ float edge_mag_half(const float* __restrict__ Ca,
                                               const float* __restrict__ Cb,
                                               const float* __restrict__ Cc) {
  const float g1  = __builtin_fmaf(2.0f, Cb[0], Ca[0] + Cc[0]);   // Sx
  const float g2  = __builtin_fmaf(2.0f, Cb[1], Ca[1] + Cc[1]);   // Sy
  const float g3  = Cc[2] - Ca[2];                                // Sz
  const float Azx = __builtin_fmaf(2.0f, Cb[3], Ca[3] + Cc[3]);   // s_z e_y d_x
  const float Azy = __builtin_fmaf(2.0f, Cb[4], Ca[4] + Cc[4]);   // s_z d_y e_x
  const float Axz = Cc[5] - Ca[5];                                // d_z e_y s_x
  const float Axy = g2 - Cb[1];                                   // e_z d_y s_x
  const float Ayx = g1 - Cb[0];                                   // e_z s_y d_x
  const float Ayz = Cc[6] - Ca[6];                                // d_z s_y e_x
  const float g4 = Azx - Azy, g5 = Azx + Azy;                     // Sd11, Sd12
  const float g6 = Axz - Axy, g7 = Axz + Axy;                     // Sd21, Sd22
  const float g8 = Ayx - Ayz, g9 = Ayx + Ayz;                     // Sd31, Sd32
  float s = __builtin_fmaf(g1, g1, 1e-12f);
  s = __builtin_fmaf(g2, g2, s); s = __builtin_fmaf(g3, g3, s);
  s = __builtin_fmaf(g4, g4, s); s = __builtin_fmaf(g5, g5, s);
  s = __builtin_fmaf(g6, g6, s); s = __builtin_fmaf(g7, g7, s);
  s = __builtin_fmaf(g8, g8, s); s = __builtin_fmaf(g9, g9, s);
  return 0.5f * sqrtf(s);
}

__global__ __launch_bounds__(256)
void gme_loss_kernel(const float* __restrict__ y,
                     const float* __restrict__ yp,
                     float* __restrict__ out) {
  const int tx  = threadIdx.x;           // D axis
  const int ty  = threadIdx.y;           // W axis
  const int tid = ty * TX + tx;

  const int bx = blockIdx.x;             // 4 x-tiles * 16 y-tiles
  const int x0 = (bx & 3) * TX;
  const int y0 = (bx >> 2) * TY;
  const int z0 = blockIdx.y * ZC;
  const int b  = blockIdx.z;

  __shared__ __align__(16) float lds[2][2][PLANE];   // [vol][buf][...]
  __shared__ float red[4];

  // ---- staging assignment: one float4 slot per thread (tid < 200) ----
  const bool has_slot = tid < 2 * NSLOT;
  bool sok = false;
  const float* gp = nullptr;             // global base (z=0) for this slot
  float* w0 = nullptr; float* w1 = nullptr;
  if (has_slot) {
    const int vol = tid >= NSLOT;        // 0 = y, 1 = yp
    const int s   = tid - vol * NSLOT;
    const int ly  = s / QPR;
    const int lx  = s - ly * QPR;
    const int py  = y0 - 1 + ly;
    const int px  = x0 - 4 + 4 * lx;
    sok = (py >= 0) & (py < YDIM) & (px >= 0) & (px <= XDIM - 4);
    const float* src = vol ? yp : y;
    gp = src + (size_t)b * 2 * CS + (size_t)py * XDIM + px;
    w0 = &lds[vol][0][ly * LW + lx * 4];
    w1 = &lds[vol][1][ly * LW + lx * 4];
  }

  // ---- hoisted LDS read bases (output voxel x0+tx needs cols tx+3..tx+5) ----
  const int ridx = ty * LW + tx + 3;
  const float* rY0 = &lds[0][0][ridx];
  const float* rY1 = &lds[0][1][ridx];
  const float* rP0 = &lds[1][0][ridx];
  const float* rP1 = &lds[1][1][ridx];

  // prefetch helper
  auto prefetch = [&](int zc) -> float4 {
    float4 v = make_float4(0.f, 0.f, 0.f, 0.f);
    if (sok && (unsigned)zc < (unsigned)ZDIM) {
      const float* p = gp + (size_t)zc * YX;
      const float4 a = *(const float4*)p;
      const float4 c = *(const float4*)(p + CS);
      v.x = a.x + c.x; v.y = a.y + c.y; v.z = a.z + c.z; v.w = a.w + c.w;
    }
    return v;
  };

  // modulo-3 combo storage (roles rotate; unroll makes indices constant)
  float KY[3][7] = {}, KP[3][7] = {};
  float acc = 0.0f;

  float4 pf = prefetch(z0 - 1);

#pragma unroll 6
  for (int i = 0; i < ZC + 2; ++i) {           // 18 iterations, zc = z0-1+i
    const int zc = z0 - 1 + i;
    // stage plane zc into buffer (i&1)
    if (has_slot) {
      float* w = (i & 1) ? w1 : w0;
      *(float4*)w = pf;
    }
    if (i < ZC + 1) pf = prefetch(zc + 1);     // overlap next-plane load w/ compute
    __syncthreads();

    float* Cc_y = KY[i % 3];
    float* Cc_p = KP[i % 3];
    plane_combos((i & 1) ? rY1 : rY0, Cc_y);
    plane_combos((i & 1) ? rP1 : rP0, Cc_p);

    if (i >= 2) {                               // emit output plane zc-1
      const float* Ca_y = KY[(i + 1) % 3];      // plane zc-2
      const float* Cb_y = KY[(i + 2) % 3];      // plane zc-1
      const float* Ca_p = KP[(i + 1) % 3];
      const float* Cb_p = KP[(i + 2) % 3];
      const float my = edge_mag_half(Ca_y, Cb_y, Cc_y);
      const float mp = edge_mag_half(Ca_p, Cb_p, Cc_p);
      const float d = my - mp;
      acc = __builtin_fmaf(d, d, acc);
    }
  }

  // ---- block reduction ----
#pragma unroll
  for (int off = 32; off > 0; off >>= 1) acc += __shfl_down(acc, off);
  const int lane = tid & 63;
  const int wave = tid >> 6;
  if (lane == 0) red[wave] = acc;
  __syncthreads();
  if (tid == 0) {
    const float s = (red[0] + red[1] + red[2] + red[3]) * INV_N;
    atomicAdd(out, s);
  }
}

}  // namespace

extern "C" void kernel_launch(void* const* d_in, const int* in_sizes, int n_in,
                              void* d_out, int out_size, void* d_ws, size_t ws_size,
                              hipStream_t stream) {
  const float* y  = (const float*)d_in[0];
  const float* yp = (const float*)d_in[1];
  float* out = (float*)d_out;

  // d_out is poisoned before every launch: zero via memset node (graph-capturable)
  hipMemsetAsync(out, 0, sizeof(float), stream);

  dim3 block(TX, TY, 1);                        // 256 threads
  dim3 grid((XDIM / TX) * (YDIM / TY),          // 64 (D,W) tiles
            ZDIM / ZC,                          // 8 H chunks
            2);                                 // batch
  gme_loss_kernel<<<grid, block, 0, stream>>>(y, yp, out);
}